// Round 8
// baseline (241.786 us; speedup 1.0000x reference)
//
#include <hip/hip_runtime.h>
#include <math.h>

namespace {

constexpr int S   = 2048;
constexpr int D   = 1024;   // d_model (= K for all GEMMs)
constexpr int H   = 16;     // heads
constexpr int DH  = 64;     // head dim
constexpr int B   = 2;      // batch
constexpr int M   = B * S;  // 4096 rows

typedef __attribute__((ext_vector_type(8)))  short bf16x8;   // 8 bf16 = 4 VGPR
typedef __attribute__((ext_vector_type(4)))  float f32x4;
typedef __attribute__((ext_vector_type(16))) float f32x16;

__device__ __forceinline__ unsigned short f2bf(float f) {
    unsigned u = __builtin_bit_cast(unsigned, f);
    u += 0x7fffu + ((u >> 16) & 1u);          // round-to-nearest-even
    return (unsigned short)(u >> 16);
}

__device__ __forceinline__ unsigned cvt_pk_bf16(float lo, float hi) {
    unsigned r;
    asm("v_cvt_pk_bf16_f32 %0, %1, %2" : "=v"(r) : "v"(lo), "v"(hi));
    return r;
}

// async global->LDS, 16B per lane. LDS dest = wave-uniform base + lane*16.
__device__ __forceinline__ void gload16(const void* g, void* l) {
    __builtin_amdgcn_global_load_lds(
        (const __attribute__((address_space(1))) void*)g,
        (__attribute__((address_space(3))) void*)l, 16, 0, 0);
}

// ---------------------------------------------------------------------------
// convert_x: x fp32 [4096][1024] -> bf16
// ---------------------------------------------------------------------------
__global__ __launch_bounds__(256) void convert_x(
    const float* __restrict__ x, unsigned short* __restrict__ xb)
{
    const int i = (blockIdx.x * 256 + threadIdx.x) * 8;
    float4 a = *(const float4*)&x[i];
    float4 b = *(const float4*)&x[i + 4];
    ushort4 lo, hi;
    lo.x = f2bf(a.x); lo.y = f2bf(a.y); lo.z = f2bf(a.z); lo.w = f2bf(a.w);
    hi.x = f2bf(b.x); hi.y = f2bf(b.y); hi.z = f2bf(b.z); hi.w = f2bf(b.w);
    *(ushort4*)&xb[i]     = lo;
    *(ushort4*)&xb[i + 4] = hi;
}

// ---------------------------------------------------------------------------
// convert_w: W fp32 [k][n] -> Wt bf16 [mat][n][k] (transposed, n-major)
// ---------------------------------------------------------------------------
__global__ __launch_bounds__(64) void convert_w(
    const float* __restrict__ Wq, const float* __restrict__ Wk,
    const float* __restrict__ Wv, const float* __restrict__ Wo,
    unsigned short* __restrict__ Wt)
{
    const int mat = blockIdx.z;
    const float* W = (mat == 0) ? Wq : (mat == 1) ? Wk : (mat == 2) ? Wv : Wo;
    const int n  = blockIdx.y * 64 + threadIdx.x;
    const int k0 = blockIdx.x * 8;
    ushort4 u0, u1;
    u0.x = f2bf(W[(size_t)(k0 + 0) * D + n]);
    u0.y = f2bf(W[(size_t)(k0 + 1) * D + n]);
    u0.z = f2bf(W[(size_t)(k0 + 2) * D + n]);
    u0.w = f2bf(W[(size_t)(k0 + 3) * D + n]);
    u1.x = f2bf(W[(size_t)(k0 + 4) * D + n]);
    u1.y = f2bf(W[(size_t)(k0 + 5) * D + n]);
    u1.z = f2bf(W[(size_t)(k0 + 6) * D + n]);
    u1.w = f2bf(W[(size_t)(k0 + 7) * D + n]);
    unsigned short* o = Wt + (size_t)mat * D * D + (size_t)n * D + k0;
    *(ushort4*)&o[0] = u0;
    *(ushort4*)&o[4] = u1;
}

// ---------------------------------------------------------------------------
// QKV GEMM, bf16 MFMA 16x16x32. 128x128 tile, BK=32, 4 waves (2x2).
// 2-phase double-buffered global_load_lds staging: STAGE(next) issued before
// compute(cur); one vmcnt(0)+barrier per K-step (T3 minimum pipeline).
// ---------------------------------------------------------------------------
__global__ __launch_bounds__(256) void gemm_qkv(
    const unsigned short* __restrict__ xb, const unsigned short* __restrict__ Wt,
    unsigned short* __restrict__ Qb, unsigned short* __restrict__ Kb,
    unsigned short* __restrict__ Vt)
{
    __shared__ unsigned short As[2][128 * 32];
    __shared__ unsigned short Bs[2][128 * 32];

    const int tid = threadIdx.x;
    const int l  = tid & 63;
    const int w  = tid >> 6;
    const int lr = l & 15;
    const int g  = l >> 4;
    const int wr = w >> 1, wc = w & 1;

    const int bm  = blockIdx.y;
    const int bnl = blockIdx.x;          // 0..23
    const int mat = bnl >> 3;            // 0..2
    const int n0  = (bnl & 7) * 128;
    const int m0  = bm * 128;
    const unsigned short* Bp = Wt + (size_t)mat * D * D;

    const int lrow = l >> 2;             // 0..15 row within 16-row chunk
    const int lcol = (l & 3) * 8;        // 0,8,16,24

    f32x4 acc[4][4];
    #pragma unroll
    for (int i = 0; i < 4; ++i)
        #pragma unroll
        for (int j = 0; j < 4; ++j) acc[i][j] = (f32x4){0.f, 0.f, 0.f, 0.f};

#define QKV_STAGE(buf, kk0)                                                       \
    {                                                                             \
        _Pragma("unroll")                                                         \
        for (int p = 0; p < 2; ++p) {                                             \
            const int c = w * 2 + p;                                              \
            gload16(&xb[(size_t)(m0 + c * 16 + lrow) * D + (kk0) + lcol],         \
                    &As[buf][c * 512]);                                           \
            gload16(&Bp[(size_t)(n0 + c * 16 + lrow) * D + (kk0) + lcol],         \
                    &Bs[buf][c * 512]);                                           \
        }                                                                         \
    }

    QKV_STAGE(0, 0);
    __syncthreads();
    int cur = 0;
    for (int k0 = 0; k0 < D; k0 += 32) {
        if (k0 + 32 < D) QKV_STAGE(cur ^ 1, k0 + 32);
        bf16x8 af[4], bfr[4];
        #pragma unroll
        for (int i = 0; i < 4; ++i) {
            af[i]  = *(const bf16x8*)&As[cur][(wr * 64 + i * 16 + lr) * 32 + g * 8];
            bfr[i] = *(const bf16x8*)&Bs[cur][(wc * 64 + i * 16 + lr) * 32 + g * 8];
        }
        #pragma unroll
        for (int mi = 0; mi < 4; ++mi)
            #pragma unroll
            for (int ni = 0; ni < 4; ++ni)
                acc[mi][ni] = __builtin_amdgcn_mfma_f32_16x16x32_bf16(
                    af[mi], bfr[ni], acc[mi][ni], 0, 0, 0);
        __syncthreads();                 // drains stage(next) + guards reuse
        cur ^= 1;
    }
#undef QKV_STAGE

    const int b      = m0 >> 11;
    const int s_base = (m0 & (S - 1)) + wr * 64;
    if (mat == 2) {
        #pragma unroll
        for (int ni = 0; ni < 4; ++ni) {
            const int n  = n0 + wc * 64 + ni * 16 + lr;
            const int bh = b * H + (n >> 6);
            unsigned short* vp = Vt + ((size_t)bh * DH + (n & 63)) * S;
            #pragma unroll
            for (int mi = 0; mi < 4; ++mi) {
                const int s0 = s_base + mi * 16 + g * 4;
                ushort4 u;
                u.x = f2bf(acc[mi][ni][0]); u.y = f2bf(acc[mi][ni][1]);
                u.z = f2bf(acc[mi][ni][2]); u.w = f2bf(acc[mi][ni][3]);
                *(ushort4*)&vp[s0] = u;
            }
        }
    } else {
        unsigned short* Op = (mat == 0) ? Qb : Kb;
        #pragma unroll
        for (int mi = 0; mi < 4; ++mi)
            #pragma unroll
            for (int r = 0; r < 4; ++r) {
                const int s = s_base + mi * 16 + g * 4 + r;
                #pragma unroll
                for (int ni = 0; ni < 4; ++ni) {
                    const int n  = n0 + wc * 64 + ni * 16 + lr;
                    const int bh = b * H + (n >> 6);
                    Op[((size_t)bh * S + s) * DH + (n & 63)] = f2bf(acc[mi][ni][r]);
                }
            }
    }
}

// ---------------------------------------------------------------------------
// Output GEMM, bf16 MFMA, 2-phase double-buffered staging (same pattern).
// ---------------------------------------------------------------------------
__global__ __launch_bounds__(256) void gemm_out(
    const unsigned short* __restrict__ ctxb, const unsigned short* __restrict__ Wot,
    const float* __restrict__ bo, float* __restrict__ out)
{
    __shared__ unsigned short As[2][64 * 32];
    __shared__ unsigned short Bs[2][128 * 32];

    const int tid = threadIdx.x;
    const int l  = tid & 63;
    const int w  = tid >> 6;
    const int lr = l & 15;
    const int g  = l >> 4;
    const int wr = w >> 1, wc = w & 1;

    const int m0 = blockIdx.y * 64;
    const int n0 = blockIdx.x * 128;

    const int lrow = l >> 2;
    const int lcol = (l & 3) * 8;

    f32x4 acc[2][4];
    #pragma unroll
    for (int i = 0; i < 2; ++i)
        #pragma unroll
        for (int j = 0; j < 4; ++j) acc[i][j] = (f32x4){0.f, 0.f, 0.f, 0.f};

#define OUT_STAGE(buf, kk0)                                                       \
    {                                                                             \
        gload16(&ctxb[(size_t)(m0 + w * 16 + lrow) * D + (kk0) + lcol],           \
                &As[buf][w * 512]);                                               \
        _Pragma("unroll")                                                         \
        for (int p = 0; p < 2; ++p) {                                             \
            const int c = w * 2 + p;                                              \
            gload16(&Wot[(size_t)(n0 + c * 16 + lrow) * D + (kk0) + lcol],        \
                    &Bs[buf][c * 512]);                                           \
        }                                                                         \
    }

    OUT_STAGE(0, 0);
    __syncthreads();
    int cur = 0;
    for (int k0 = 0; k0 < D; k0 += 32) {
        if (k0 + 32 < D) OUT_STAGE(cur ^ 1, k0 + 32);
        bf16x8 af[2], bfr[4];
        #pragma unroll
        for (int i = 0; i < 2; ++i)
            af[i] = *(const bf16x8*)&As[cur][(wr * 32 + i * 16 + lr) * 32 + g * 8];
        #pragma unroll
        for (int i = 0; i < 4; ++i)
            bfr[i] = *(const bf16x8*)&Bs[cur][(wc * 64 + i * 16 + lr) * 32 + g * 8];
        #pragma unroll
        for (int mi = 0; mi < 2; ++mi)
            #pragma unroll
            for (int ni = 0; ni < 4; ++ni)
                acc[mi][ni] = __builtin_amdgcn_mfma_f32_16x16x32_bf16(
                    af[mi], bfr[ni], acc[mi][ni], 0, 0, 0);
        __syncthreads();
        cur ^= 1;
    }
#undef OUT_STAGE

    #pragma unroll
    for (int mi = 0; mi < 2; ++mi)
        #pragma unroll
        for (int ni = 0; ni < 4; ++ni) {
            const int n = n0 + wc * 64 + ni * 16 + lr;
            const float bias = bo[n];
            #pragma unroll
            for (int r = 0; r < 4; ++r) {
                const int m = m0 + wr * 32 + mi * 16 + g * 4 + r;
                out[(size_t)m * D + n] = acc[mi][ni][r] + bias;
            }
        }
}

// ---------------------------------------------------------------------------
// Causal flash attention, 32x32x16 bf16 MFMA, swapped operands.
// Block = 4 waves x 32 q-rows = 128 q-rows. KV tiles of 64 double-buffered
// in LDS via global_load_lds; source-pre-swizzled (rule 21).
// Grid mapping: XCD-pinned bh (4/XCD, KV 2MB L2-resident) AND per-CU
// load-balance: dispatch round 0 (jj<32) takes qt=15-k heavy-first on bh
// {4x,4x+1}; round 1 takes qt=k on bh {4x+2,4x+3}. A CU's two blocks pair
// (15-k, k) -> uniform 34 tile-iterations per CU.
// ---------------------------------------------------------------------------
__global__ __launch_bounds__(256, 2) void attn_mfma32(
    const unsigned short* __restrict__ Qb, const unsigned short* __restrict__ Kb,
    const unsigned short* __restrict__ Vt, unsigned short* __restrict__ ctxb)
{
    __shared__ unsigned short Ks[2][64 * 64];
    __shared__ unsigned short Vs[2][64 * 64];

    const int tid = threadIdx.x;
    const int l   = tid & 63;
    const int w   = tid >> 6;            // wave 0..3
    const int l31 = l & 31;
    const int hi  = l >> 5;

    // balanced XCD-pinned mapping (see header comment)
    const int lid = blockIdx.x;          // 0..511
    const int xcd = lid & 7;
    const int jj  = lid >> 3;            // 0..63
    const int rnd = jj >> 5;             // dispatch round 0/1
    const int pos = jj & 31;
    const int sub = pos >> 4;            // 0/1
    const int k16 = pos & 15;
    const int bh  = xcd * 4 + rnd * 2 + sub;
    const int qt  = rnd ? k16 : 15 - k16;
    const int q0w = qt * 128 + w * 32;   // this wave's first q-row
    const int Fw  = q0w >> 6;            // this wave's diagonal kv-tile
    const int NT  = 2 * qt + 2;          // kv tiles for the block

    const unsigned short* Qp = Qb + (size_t)bh * S * DH;
    const unsigned short* Kp = Kb + (size_t)bh * S * DH;
    const unsigned short* Vp = Vt + (size_t)bh * DH * S;

    // Q fragments, held whole kernel
    bf16x8 qf[4];
    #pragma unroll
    for (int kk = 0; kk < 4; ++kk)
        qf[kk] = *(const bf16x8*)&Qp[(size_t)(q0w + l31) * DH + kk * 16 + hi * 8];

    f32x16 acc0 = {}, acc1 = {};
    float m = -1e30f, ll = 0.f;

    // staging: tile = 64x64 bf16 (8KB) each for K and V^T; 8 chunks of 1KB
    // (8 rows each); wave w stages chunks {2w, 2w+1} of each.
    // source col pre-swizzled: slot (l&7) ^ (row&7), row&7 == l>>3.
    const int srow = l >> 3;                       // row within chunk (0..7)
    const int ssw  = 8 * ((l & 7) ^ srow);         // swizzled col (elements)

#define ATTN_STAGE(buf, t)                                                    \
    {                                                                         \
        const int kv0s = (t) * 64;                                            \
        _Pragma("unroll")                                                     \
        for (int p = 0; p < 2; ++p) {                                         \
            const int c   = w * 2 + p;                                        \
            const int row = c * 8 + srow;                                     \
            gload16(Kp + (size_t)(kv0s + row) * DH + ssw, &Ks[buf][c * 512]); \
            gload16(Vp + (size_t)row * S + kv0s + ssw, &Vs[buf][c * 512]);    \
        }                                                                     \
    }

    ATTN_STAGE(0, 0);
    __syncthreads();

    for (int t = 0; t < NT; ++t) {
        const int cur = t & 1;
        if (t + 1 < NT) ATTN_STAGE(cur ^ 1, t + 1);

        if (t <= Fw) {                                // wave-uniform
            const int kv0  = t * 64;
            const bool diag = (t == Fw);

            // QK^T: two 32x32 C-tiles (kv rows 0-31 / 32-63), ILP 2
            f32x16 stl = {}, sth = {};
            #pragma unroll
            for (int kk = 0; kk < 4; ++kk) {
                const int cc = kk * 2 + hi;
                bf16x8 kl = *(const bf16x8*)&Ks[cur][l31 * 64 + ((cc ^ (l31 & 7)) * 8)];
                bf16x8 kh = *(const bf16x8*)&Ks[cur][(32 + l31) * 64 + ((cc ^ (l31 & 7)) * 8)];
                stl = __builtin_amdgcn_mfma_f32_32x32x16_bf16(kl, qf[kk], stl, 0, 0, 0);
                sth = __builtin_amdgcn_mfma_f32_32x32x16_bf16(kh, qf[kk], sth, 0, 0, 0);
            }

            const int qg = q0w + l31;
            float sc0[16], sc1[16];
            float pmax = -3e38f;
            #pragma unroll
            for (int r = 0; r < 16; ++r) {
                const int koff = (r & 3) + 8 * (r >> 2) + 4 * hi;
                float a = stl[r] * 0.125f;            // 1/sqrt(64)
                float b = sth[r] * 0.125f;
                if (diag) {
                    if (kv0 + koff > qg)      a = -3e38f;
                    if (kv0 + 32 + koff > qg) b = -3e38f;
                }
                sc0[r] = a; sc1[r] = b;
                pmax = fmaxf(pmax, fmaxf(a, b));
            }
            pmax = fmaxf(pmax, __shfl_xor(pmax, 32));

            if (!__all(pmax <= m + 8.f)) {            // T13 defer-max
                const float newm = fmaxf(m, pmax);
                const float corr = __expf(m - newm);
                ll *= corr;
                #pragma unroll
                for (int r = 0; r < 16; ++r) { acc0[r] *= corr; acc1[r] *= corr; }
                m = newm;
            }
            float p0[16], p1[16], psum = 0.f;
            #pragma unroll
            for (int r = 0; r < 16; ++r) {
                p0[r] = __expf(sc0[r] - m); psum += p0[r];
                p1[r] = __expf(sc1[r] - m); psum += p1[r];
            }
            ll += psum + __shfl_xor(psum, 32);

            unsigned pw[16];
            #pragma unroll
            for (int tt = 0; tt < 8; ++tt) {
                pw[tt]     = cvt_pk_bf16(p0[2 * tt], p0[2 * tt + 1]);
                pw[8 + tt] = cvt_pk_bf16(p1[2 * tt], p1[2 * tt + 1]);
            }

            // PV: O^T += V^T . P^T over 4 k-chunks of 16
            __builtin_amdgcn_s_setprio(1);
            #pragma unroll
            for (int ck = 0; ck < 4; ++ck) {
                const int t00 = 2 * ((2 * ck) & 3) + 8 * (ck >> 1);      // h=0
                const int t10 = 2 * ((2 * ck + 1) & 3) + 8 * (ck >> 1);  // h=1
                const unsigned sw0 = hi ? pw[t10]     : pw[t00];
                const unsigned sw1 = hi ? pw[t10 + 1] : pw[t00 + 1];
                const unsigned e0i = hi ? pw[t00]     : pw[t10];
                const unsigned e1i = hi ? pw[t00 + 1] : pw[t10 + 1];
                const unsigned e0  = __shfl_xor(e0i, 32);
                const unsigned e1  = __shfl_xor(e1i, 32);
                union { unsigned u[4]; bf16x8 v; } pb;
                pb.u[0] = hi ? e0  : sw0;
                pb.u[1] = hi ? e1  : sw1;
                pb.u[2] = hi ? sw0 : e0;
                pb.u[3] = hi ? sw1 : e1;
                const int cc = ck * 2 + hi;
                bf16x8 v0 = *(const bf16x8*)&Vs[cur][l31 * 64 + ((cc ^ (l31 & 7)) * 8)];
                bf16x8 v1 = *(const bf16x8*)&Vs[cur][(32 + l31) * 64 + ((cc ^ (l31 & 7)) * 8)];
                acc0 = __builtin_amdgcn_mfma_f32_32x32x16_bf16(v0, pb.v, acc0, 0, 0, 0);
                acc1 = __builtin_amdgcn_mfma_f32_32x32x16_bf16(v1, pb.v, acc1, 0, 0, 0);
            }
            __builtin_amdgcn_s_setprio(0);
        }
        __syncthreads();                  // vmcnt(0)+barrier: next buffer ready
    }

    // epilogue: O^T row d = (reg&3)+8*(reg>>2)+4*hi (+32 for acc1), col q
    const float inv = 1.f / ll;
    const int bb = bh >> 4, hh = bh & (H - 1);
    const int q  = q0w + l31;
    unsigned short* op = ctxb + ((size_t)(bb * S + q)) * D + hh * DH;
    #pragma unroll
    for (int t = 0; t < 8; ++t) {
        const int r0 = 2 * t;
        const int d  = (r0 & 3) + 8 * (r0 >> 2) + 4 * hi;
        *(unsigned*)&op[d]      = cvt_pk_bf16(acc0[r0] * inv, acc0[r0 + 1] * inv);
        *(unsigned*)&op[32 + d] = cvt_pk_bf16(acc1[r0] * inv, acc1[r0 + 1] * inv);
    }
#undef ATTN_STAGE
}

} // namespace

extern "C" void kernel_launch(void* const* d_in, const int* in_sizes, int n_in,
                              void* d_out, int out_size, void* d_ws, size_t ws_size,
                              hipStream_t stream) {
    const float* x  = (const float*)d_in[0];
    const float* Wq = (const float*)d_in[1];
    const float* Wk = (const float*)d_in[2];
    const float* Wv = (const float*)d_in[3];
    const float* Wo = (const float*)d_in[4];
    const float* bo = (const float*)d_in[5];
    float* out = (float*)d_out;

    // ws (bf16): xb 8MB | Wt 4x2MB | Qb 8MB | Kb 8MB | Vt 8MB | ctxb 8MB = 48MB
    unsigned short* xb   = (unsigned short*)d_ws;
    unsigned short* Wt   = xb + (size_t)M * D;
    unsigned short* Qb   = Wt + (size_t)4 * D * D;
    unsigned short* Kb   = Qb + (size_t)M * D;
    unsigned short* Vtp  = Kb + (size_t)M * D;
    unsigned short* ctxb = Vtp + (size_t)M * D;

    convert_x<<<dim3((M * D) / (256 * 8)), 256, 0, stream>>>(x, xb);
    convert_w<<<dim3(D / 8, D / 64, 4), 64, 0, stream>>>(Wq, Wk, Wv, Wo, Wt);
    gemm_qkv<<<dim3(24, M / 128), 256, 0, stream>>>(xb, Wt, Qb, Kb, Vtp);
    attn_mfma32<<<dim3(512), 256, 0, stream>>>(Qb, Kb, Vtp, ctxb);
    gemm_out<<<dim3(D / 128, M / 64), 256, 0, stream>>>(
        ctxb, Wt + (size_t)3 * D * D, bo, out);
}

// Round 9
// 205.593 us; speedup vs baseline: 1.1760x; 1.1760x over previous
//
#include <hip/hip_runtime.h>
#include <math.h>

namespace {

constexpr int S   = 2048;
constexpr int D   = 1024;   // d_model (= K for all GEMMs)
constexpr int H   = 16;     // heads
constexpr int DH  = 64;     // head dim
constexpr int B   = 2;      // batch
constexpr int M   = B * S;  // 4096 rows

typedef __attribute__((ext_vector_type(8)))  short bf16x8;   // 8 bf16 = 4 VGPR
typedef __attribute__((ext_vector_type(4)))  float f32x4;
typedef __attribute__((ext_vector_type(16))) float f32x16;

__device__ __forceinline__ unsigned short f2bf(float f) {
    unsigned u = __builtin_bit_cast(unsigned, f);
    u += 0x7fffu + ((u >> 16) & 1u);          // round-to-nearest-even
    return (unsigned short)(u >> 16);
}

__device__ __forceinline__ unsigned cvt_pk_bf16(float lo, float hi) {
    unsigned r;
    asm("v_cvt_pk_bf16_f32 %0, %1, %2" : "=v"(r) : "v"(lo), "v"(hi));
    return r;
}

// async global->LDS, 16B per lane. LDS dest = wave-uniform base + lane*16.
__device__ __forceinline__ void gload16(const void* g, void* l) {
    __builtin_amdgcn_global_load_lds(
        (const __attribute__((address_space(1))) void*)g,
        (__attribute__((address_space(3))) void*)l, 16, 0, 0);
}

// ---------------------------------------------------------------------------
// convert_x: x fp32 [4096][1024] -> bf16
// ---------------------------------------------------------------------------
__global__ __launch_bounds__(256) void convert_x(
    const float* __restrict__ x, unsigned short* __restrict__ xb)
{
    const int i = (blockIdx.x * 256 + threadIdx.x) * 8;
    float4 a = *(const float4*)&x[i];
    float4 b = *(const float4*)&x[i + 4];
    ushort4 lo, hi;
    lo.x = f2bf(a.x); lo.y = f2bf(a.y); lo.z = f2bf(a.z); lo.w = f2bf(a.w);
    hi.x = f2bf(b.x); hi.y = f2bf(b.y); hi.z = f2bf(b.z); hi.w = f2bf(b.w);
    *(ushort4*)&xb[i]     = lo;
    *(ushort4*)&xb[i + 4] = hi;
}

// ---------------------------------------------------------------------------
// convert_w: W fp32 [k][n] -> Wt bf16 [mat][n][k] (transposed, n-major)
// ---------------------------------------------------------------------------
__global__ __launch_bounds__(64) void convert_w(
    const float* __restrict__ Wq, const float* __restrict__ Wk,
    const float* __restrict__ Wv, const float* __restrict__ Wo,
    unsigned short* __restrict__ Wt)
{
    const int mat = blockIdx.z;
    const float* W = (mat == 0) ? Wq : (mat == 1) ? Wk : (mat == 2) ? Wv : Wo;
    const int n  = blockIdx.y * 64 + threadIdx.x;
    const int k0 = blockIdx.x * 8;
    ushort4 u0, u1;
    u0.x = f2bf(W[(size_t)(k0 + 0) * D + n]);
    u0.y = f2bf(W[(size_t)(k0 + 1) * D + n]);
    u0.z = f2bf(W[(size_t)(k0 + 2) * D + n]);
    u0.w = f2bf(W[(size_t)(k0 + 3) * D + n]);
    u1.x = f2bf(W[(size_t)(k0 + 4) * D + n]);
    u1.y = f2bf(W[(size_t)(k0 + 5) * D + n]);
    u1.z = f2bf(W[(size_t)(k0 + 6) * D + n]);
    u1.w = f2bf(W[(size_t)(k0 + 7) * D + n]);
    unsigned short* o = Wt + (size_t)mat * D * D + (size_t)n * D + k0;
    *(ushort4*)&o[0] = u0;
    *(ushort4*)&o[4] = u1;
}

// ---------------------------------------------------------------------------
// QKV GEMM, bf16 MFMA 16x16x32. 128x128 tile, BK=32, 4 waves (2x2).
// STATIC dual-buffer (named arrays, unroll-2): the prefetch global_load_lds
// targets a distinct named array, so alias analysis cannot force a vmcnt(0)
// drain before the ds_reads of the compute buffer.
// ---------------------------------------------------------------------------
__global__ __launch_bounds__(256) void gemm_qkv(
    const unsigned short* __restrict__ xb, const unsigned short* __restrict__ Wt,
    unsigned short* __restrict__ Qb, unsigned short* __restrict__ Kb,
    unsigned short* __restrict__ Vt)
{
    __shared__ unsigned short As0[128 * 32];
    __shared__ unsigned short As1[128 * 32];
    __shared__ unsigned short Bs0[128 * 32];
    __shared__ unsigned short Bs1[128 * 32];

    const int tid = threadIdx.x;
    const int l  = tid & 63;
    const int w  = tid >> 6;
    const int lr = l & 15;
    const int g  = l >> 4;
    const int wr = w >> 1, wc = w & 1;

    const int bm  = blockIdx.y;
    const int bnl = blockIdx.x;          // 0..23
    const int mat = bnl >> 3;            // 0..2
    const int n0  = (bnl & 7) * 128;
    const int m0  = bm * 128;
    const unsigned short* Bp = Wt + (size_t)mat * D * D;

    const int lrow = l >> 2;             // 0..15 row within 16-row chunk
    const int lcol = (l & 3) * 8;        // 0,8,16,24

    f32x4 acc[4][4];
    #pragma unroll
    for (int i = 0; i < 4; ++i)
        #pragma unroll
        for (int j = 0; j < 4; ++j) acc[i][j] = (f32x4){0.f, 0.f, 0.f, 0.f};

#define QKV_STAGE(AD, BD, kk0)                                                    \
    {                                                                             \
        _Pragma("unroll")                                                         \
        for (int p = 0; p < 2; ++p) {                                             \
            const int c = w * 2 + p;                                              \
            gload16(&xb[(size_t)(m0 + c * 16 + lrow) * D + (kk0) + lcol],         \
                    &AD[c * 512]);                                                \
            gload16(&Bp[(size_t)(n0 + c * 16 + lrow) * D + (kk0) + lcol],         \
                    &BD[c * 512]);                                                \
        }                                                                         \
    }

#define QKV_COMP(AS, BS)                                                          \
    {                                                                             \
        bf16x8 af[4], bfr[4];                                                     \
        _Pragma("unroll")                                                         \
        for (int i = 0; i < 4; ++i) {                                             \
            af[i]  = *(const bf16x8*)&AS[(wr * 64 + i * 16 + lr) * 32 + g * 8];   \
            bfr[i] = *(const bf16x8*)&BS[(wc * 64 + i * 16 + lr) * 32 + g * 8];   \
        }                                                                         \
        _Pragma("unroll")                                                         \
        for (int mi = 0; mi < 4; ++mi)                                            \
            _Pragma("unroll")                                                     \
            for (int ni = 0; ni < 4; ++ni)                                        \
                acc[mi][ni] = __builtin_amdgcn_mfma_f32_16x16x32_bf16(            \
                    af[mi], bfr[ni], acc[mi][ni], 0, 0, 0);                       \
    }

    QKV_STAGE(As0, Bs0, 0);
    __syncthreads();
    for (int k0 = 0; k0 < D; k0 += 64) {
        QKV_STAGE(As1, Bs1, k0 + 32);          // k0+32 <= 992 < D always
        QKV_COMP(As0, Bs0);
        __syncthreads();
        if (k0 + 64 < D) QKV_STAGE(As0, Bs0, k0 + 64);
        QKV_COMP(As1, Bs1);
        __syncthreads();
    }
#undef QKV_STAGE
#undef QKV_COMP

    const int b      = m0 >> 11;
    const int s_base = (m0 & (S - 1)) + wr * 64;
    if (mat == 2) {
        #pragma unroll
        for (int ni = 0; ni < 4; ++ni) {
            const int n  = n0 + wc * 64 + ni * 16 + lr;
            const int bh = b * H + (n >> 6);
            unsigned short* vp = Vt + ((size_t)bh * DH + (n & 63)) * S;
            #pragma unroll
            for (int mi = 0; mi < 4; ++mi) {
                const int s0 = s_base + mi * 16 + g * 4;
                ushort4 u;
                u.x = f2bf(acc[mi][ni][0]); u.y = f2bf(acc[mi][ni][1]);
                u.z = f2bf(acc[mi][ni][2]); u.w = f2bf(acc[mi][ni][3]);
                *(ushort4*)&vp[s0] = u;
            }
        }
    } else {
        unsigned short* Op = (mat == 0) ? Qb : Kb;
        #pragma unroll
        for (int mi = 0; mi < 4; ++mi)
            #pragma unroll
            for (int r = 0; r < 4; ++r) {
                const int s = s_base + mi * 16 + g * 4 + r;
                #pragma unroll
                for (int ni = 0; ni < 4; ++ni) {
                    const int n  = n0 + wc * 64 + ni * 16 + lr;
                    const int bh = b * H + (n >> 6);
                    Op[((size_t)bh * S + s) * DH + (n & 63)] = f2bf(acc[mi][ni][r]);
                }
            }
    }
}

// ---------------------------------------------------------------------------
// Output GEMM, bf16 MFMA — round-7 single-buffer structure (known-good,
// serves as the A/B control vs gemm_qkv's static dual-buffer).
// ---------------------------------------------------------------------------
__global__ __launch_bounds__(256) void gemm_out(
    const unsigned short* __restrict__ ctxb, const unsigned short* __restrict__ Wot,
    const float* __restrict__ bo, float* __restrict__ out)
{
    __shared__ unsigned short As[64 * 32];
    __shared__ unsigned short Bs[128 * 32];

    const int tid = threadIdx.x;
    const int l  = tid & 63;
    const int w  = tid >> 6;
    const int lr = l & 15;
    const int g  = l >> 4;
    const int wr = w >> 1, wc = w & 1;

    const int m0 = blockIdx.y * 64;
    const int n0 = blockIdx.x * 128;

    const int lrow = l >> 2;
    const int lcol = (l & 3) * 8;

    f32x4 acc[2][4];
    #pragma unroll
    for (int i = 0; i < 2; ++i)
        #pragma unroll
        for (int j = 0; j < 4; ++j) acc[i][j] = (f32x4){0.f, 0.f, 0.f, 0.f};

    for (int k0 = 0; k0 < D; k0 += 32) {
        gload16(&ctxb[(size_t)(m0 + w * 16 + lrow) * D + k0 + lcol], &As[w * 512]);
        #pragma unroll
        for (int p = 0; p < 2; ++p) {
            const int c = w * 2 + p;
            gload16(&Wot[(size_t)(n0 + c * 16 + lrow) * D + k0 + lcol], &Bs[c * 512]);
        }
        __syncthreads();
        bf16x8 af[2], bfr[4];
        #pragma unroll
        for (int i = 0; i < 2; ++i)
            af[i] = *(const bf16x8*)&As[(wr * 32 + i * 16 + lr) * 32 + g * 8];
        #pragma unroll
        for (int i = 0; i < 4; ++i)
            bfr[i] = *(const bf16x8*)&Bs[(wc * 64 + i * 16 + lr) * 32 + g * 8];
        #pragma unroll
        for (int mi = 0; mi < 2; ++mi)
            #pragma unroll
            for (int ni = 0; ni < 4; ++ni)
                acc[mi][ni] = __builtin_amdgcn_mfma_f32_16x16x32_bf16(
                    af[mi], bfr[ni], acc[mi][ni], 0, 0, 0);
        __syncthreads();
    }

    #pragma unroll
    for (int mi = 0; mi < 2; ++mi)
        #pragma unroll
        for (int ni = 0; ni < 4; ++ni) {
            const int n = n0 + wc * 64 + ni * 16 + lr;
            const float bias = bo[n];
            #pragma unroll
            for (int r = 0; r < 4; ++r) {
                const int m = m0 + wr * 32 + mi * 16 + g * 4 + r;
                out[(size_t)m * D + n] = acc[mi][ni][r] + bias;
            }
        }
}

// ---------------------------------------------------------------------------
// Causal flash attention, 32x32x16 bf16 MFMA, swapped operands.
// Block = 4 waves x 32 q-rows. KV tiles of 64 in STATIC double buffers
// (Ks0/Ks1/Vs0/Vs1, unroll-2: NT = 2qt+2 is always even). Source-pre-swizzled
// staging (rule 21). Balanced XCD-pinned grid mapping (round 8).
// ---------------------------------------------------------------------------
__global__ __launch_bounds__(256, 2) void attn_mfma32(
    const unsigned short* __restrict__ Qb, const unsigned short* __restrict__ Kb,
    const unsigned short* __restrict__ Vt, unsigned short* __restrict__ ctxb)
{
    __shared__ unsigned short Ks0[64 * 64];
    __shared__ unsigned short Ks1[64 * 64];
    __shared__ unsigned short Vs0[64 * 64];
    __shared__ unsigned short Vs1[64 * 64];

    const int tid = threadIdx.x;
    const int l   = tid & 63;
    const int w   = tid >> 6;            // wave 0..3
    const int l31 = l & 31;
    const int hi  = l >> 5;

    // balanced XCD-pinned mapping: CU's two blocks pair (15-k, k) q-tiles
    const int lid = blockIdx.x;          // 0..511
    const int xcd = lid & 7;
    const int jj  = lid >> 3;            // 0..63
    const int rnd = jj >> 5;             // dispatch round 0/1
    const int pos = jj & 31;
    const int sub = pos >> 4;            // 0/1
    const int k16 = pos & 15;
    const int bh  = xcd * 4 + rnd * 2 + sub;
    const int qt  = rnd ? k16 : 15 - k16;
    const int q0w = qt * 128 + w * 32;   // this wave's first q-row
    const int Fw  = q0w >> 6;            // this wave's diagonal kv-tile
    const int NT  = 2 * qt + 2;          // kv tiles for the block (even)

    const unsigned short* Qp = Qb + (size_t)bh * S * DH;
    const unsigned short* Kp = Kb + (size_t)bh * S * DH;
    const unsigned short* Vp = Vt + (size_t)bh * DH * S;

    // Q fragments, held whole kernel
    bf16x8 qf[4];
    #pragma unroll
    for (int kk = 0; kk < 4; ++kk)
        qf[kk] = *(const bf16x8*)&Qp[(size_t)(q0w + l31) * DH + kk * 16 + hi * 8];

    f32x16 acc0 = {}, acc1 = {};
    float m = -1e30f, ll = 0.f;

    // staging: 64x64 bf16 (8KB) per tile; 8 chunks of 1KB (8 rows each);
    // wave w stages chunks {2w, 2w+1}. Source col pre-swizzled (rule 21).
    const int srow = l >> 3;                       // row within chunk (0..7)
    const int ssw  = 8 * ((l & 7) ^ srow);         // swizzled col (elements)

#define ATTN_STAGE(KD, VD, t)                                                 \
    {                                                                         \
        const int kv0s = (t) * 64;                                            \
        _Pragma("unroll")                                                     \
        for (int p = 0; p < 2; ++p) {                                         \
            const int c   = w * 2 + p;                                        \
            const int row = c * 8 + srow;                                     \
            gload16(Kp + (size_t)(kv0s + row) * DH + ssw, &KD[c * 512]);      \
            gload16(Vp + (size_t)row * S + kv0s + ssw, &VD[c * 512]);         \
        }                                                                     \
    }

#define ATTN_STEP(KSB, VSB, TT)                                               \
    if ((TT) <= Fw) {                                                         \
        const int kv0  = (TT) * 64;                                           \
        const bool diag = ((TT) == Fw);                                       \
        f32x16 stl = {}, sth = {};                                            \
        _Pragma("unroll")                                                     \
        for (int kk = 0; kk < 4; ++kk) {                                      \
            const int cc = kk * 2 + hi;                                       \
            bf16x8 kl = *(const bf16x8*)&KSB[l31 * 64 + ((cc ^ (l31 & 7)) * 8)]; \
            bf16x8 kh = *(const bf16x8*)&KSB[(32 + l31) * 64 + ((cc ^ (l31 & 7)) * 8)]; \
            stl = __builtin_amdgcn_mfma_f32_32x32x16_bf16(kl, qf[kk], stl, 0, 0, 0); \
            sth = __builtin_amdgcn_mfma_f32_32x32x16_bf16(kh, qf[kk], sth, 0, 0, 0); \
        }                                                                     \
        const int qg = q0w + l31;                                             \
        float sc0[16], sc1[16];                                               \
        float pmax = -3e38f;                                                  \
        _Pragma("unroll")                                                     \
        for (int r = 0; r < 16; ++r) {                                        \
            const int koff = (r & 3) + 8 * (r >> 2) + 4 * hi;                 \
            float a = stl[r] * 0.125f;                                        \
            float b2 = sth[r] * 0.125f;                                       \
            if (diag) {                                                       \
                if (kv0 + koff > qg)      a  = -3e38f;                        \
                if (kv0 + 32 + koff > qg) b2 = -3e38f;                        \
            }                                                                 \
            sc0[r] = a; sc1[r] = b2;                                          \
            pmax = fmaxf(pmax, fmaxf(a, b2));                                 \
        }                                                                     \
        pmax = fmaxf(pmax, __shfl_xor(pmax, 32));                             \
        if (!__all(pmax <= m + 8.f)) {                                        \
            const float newm = fmaxf(m, pmax);                                \
            const float corr = __expf(m - newm);                              \
            ll *= corr;                                                       \
            _Pragma("unroll")                                                 \
            for (int r = 0; r < 16; ++r) { acc0[r] *= corr; acc1[r] *= corr; }\
            m = newm;                                                         \
        }                                                                     \
        float p0[16], p1[16], psum = 0.f;                                     \
        _Pragma("unroll")                                                     \
        for (int r = 0; r < 16; ++r) {                                        \
            p0[r] = __expf(sc0[r] - m); psum += p0[r];                        \
            p1[r] = __expf(sc1[r] - m); psum += p1[r];                        \
        }                                                                     \
        ll += psum + __shfl_xor(psum, 32);                                    \
        unsigned pw[16];                                                      \
        _Pragma("unroll")                                                     \
        for (int tt = 0; tt < 8; ++tt) {                                      \
            pw[tt]     = cvt_pk_bf16(p0[2 * tt], p0[2 * tt + 1]);             \
            pw[8 + tt] = cvt_pk_bf16(p1[2 * tt], p1[2 * tt + 1]);             \
        }                                                                     \
        __builtin_amdgcn_s_setprio(1);                                        \
        _Pragma("unroll")                                                     \
        for (int ck = 0; ck < 4; ++ck) {                                      \
            const int t00 = 2 * ((2 * ck) & 3) + 8 * (ck >> 1);               \
            const int t10 = 2 * ((2 * ck + 1) & 3) + 8 * (ck >> 1);           \
            const unsigned sw0 = hi ? pw[t10]     : pw[t00];                  \
            const unsigned sw1 = hi ? pw[t10 + 1] : pw[t00 + 1];              \
            const unsigned e0i = hi ? pw[t00]     : pw[t10];                  \
            const unsigned e1i = hi ? pw[t00 + 1] : pw[t10 + 1];              \
            const unsigned e0  = __shfl_xor(e0i, 32);                         \
            const unsigned e1  = __shfl_xor(e1i, 32);                         \
            union { unsigned u[4]; bf16x8 v; } pb;                            \
            pb.u[0] = hi ? e0  : sw0;                                         \
            pb.u[1] = hi ? e1  : sw1;                                         \
            pb.u[2] = hi ? sw0 : e0;                                          \
            pb.u[3] = hi ? sw1 : e1;                                          \
            const int cc = ck * 2 + hi;                                       \
            bf16x8 v0 = *(const bf16x8*)&VSB[l31 * 64 + ((cc ^ (l31 & 7)) * 8)]; \
            bf16x8 v1 = *(const bf16x8*)&VSB[(32 + l31) * 64 + ((cc ^ (l31 & 7)) * 8)]; \
            acc0 = __builtin_amdgcn_mfma_f32_32x32x16_bf16(v0, pb.v, acc0, 0, 0, 0); \
            acc1 = __builtin_amdgcn_mfma_f32_32x32x16_bf16(v1, pb.v, acc1, 0, 0, 0); \
        }                                                                     \
        __builtin_amdgcn_s_setprio(0);                                        \
    }

    ATTN_STAGE(Ks0, Vs0, 0);
    __syncthreads();

    for (int t = 0; t < NT; t += 2) {
        ATTN_STAGE(Ks1, Vs1, t + 1);          // t+1 < NT always (NT even)
        ATTN_STEP(Ks0, Vs0, t);
        __syncthreads();
        if (t + 2 < NT) ATTN_STAGE(Ks0, Vs0, t + 2);
        ATTN_STEP(Ks1, Vs1, t + 1);
        __syncthreads();
    }
#undef ATTN_STAGE
#undef ATTN_STEP

    // epilogue: O^T row d = (reg&3)+8*(reg>>2)+4*hi (+32 for acc1), col q
    const float inv = 1.f / ll;
    const int bb = bh >> 4, hh = bh & (H - 1);
    const int q  = q0w + l31;
    unsigned short* op = ctxb + ((size_t)(bb * S + q)) * D + hh * DH;
    #pragma unroll
    for (int t = 0; t < 8; ++t) {
        const int r0 = 2 * t;
        const int d  = (r0 & 3) + 8 * (r0 >> 2) + 4 * hi;
        *(unsigned*)&op[d]      = cvt_pk_bf16(acc0[r0] * inv, acc0[r0 + 1] * inv);
        *(unsigned*)&op[32 + d] = cvt_pk_bf16(acc1[r0] * inv, acc1[r0 + 1] * inv);
    }
}

} // namespace

extern "C" void kernel_launch(void* const* d_in, const int* in_sizes, int n_in,
                              void* d_out, int out_size, void* d_ws, size_t ws_size,
                              hipStream_t stream) {
    const float* x  = (const float*)d_in[0];
    const float* Wq = (const float*)d_in[1];
    const float* Wk = (const float*)d_in[2];
    const float* Wv = (const float*)d_in[3];
    const float* Wo = (const float*)d_in[4];
    const float* bo = (const float*)d_in[5];
    float* out = (float*)d_out;

    // ws (bf16): xb 8MB | Wt 4x2MB | Qb 8MB | Kb 8MB | Vt 8MB | ctxb 8MB = 48MB
    unsigned short* xb   = (unsigned short*)d_ws;
    unsigned short* Wt   = xb + (size_t)M * D;
    unsigned short* Qb   = Wt + (size_t)4 * D * D;
    unsigned short* Kb   = Qb + (size_t)M * D;
    unsigned short* Vtp  = Kb + (size_t)M * D;
    unsigned short* ctxb = Vtp + (size_t)M * D;

    convert_x<<<dim3((M * D) / (256 * 8)), 256, 0, stream>>>(x, xb);
    convert_w<<<dim3(D / 8, D / 64, 4), 64, 0, stream>>>(Wq, Wk, Wv, Wo, Wt);
    gemm_qkv<<<dim3(24, M / 128), 256, 0, stream>>>(xb, Wt, Qb, Kb, Vtp);
    attn_mfma32<<<dim3(512), 256, 0, stream>>>(Qb, Kb, Vtp, ctxb);
    gemm_out<<<dim3(D / 128, M / 64), 256, 0, stream>>>(
        ctxb, Wt + (size_t)3 * D * D, bo, out);
}

// Round 10
// 194.013 us; speedup vs baseline: 1.2462x; 1.0597x over previous
//
#include <hip/hip_runtime.h>
#include <math.h>

namespace {

constexpr int S   = 2048;
constexpr int D   = 1024;   // d_model (= K for all GEMMs)
constexpr int H   = 16;     // heads
constexpr int DH  = 64;     // head dim
constexpr int B   = 2;      // batch
constexpr int M   = B * S;  // 4096 rows

typedef __attribute__((ext_vector_type(8)))  short bf16x8;   // 8 bf16 = 4 VGPR
typedef __attribute__((ext_vector_type(4)))  float f32x4;
typedef __attribute__((ext_vector_type(16))) float f32x16;

__device__ __forceinline__ unsigned short f2bf(float f) {
    unsigned u = __builtin_bit_cast(unsigned, f);
    u += 0x7fffu + ((u >> 16) & 1u);          // round-to-nearest-even
    return (unsigned short)(u >> 16);
}

__device__ __forceinline__ unsigned cvt_pk_bf16(float lo, float hi) {
    unsigned r;
    asm("v_cvt_pk_bf16_f32 %0, %1, %2" : "=v"(r) : "v"(lo), "v"(hi));
    return r;
}

// async global->LDS, 16B per lane. LDS dest = wave-uniform base + lane*16.
__device__ __forceinline__ void gload16(const void* g, void* l) {
    __builtin_amdgcn_global_load_lds(
        (const __attribute__((address_space(1))) void*)g,
        (__attribute__((address_space(3))) void*)l, 16, 0, 0);
}

// ---------------------------------------------------------------------------
// convert_x: x fp32 [4096][1024] -> bf16
// ---------------------------------------------------------------------------
__global__ __launch_bounds__(256) void convert_x(
    const float* __restrict__ x, unsigned short* __restrict__ xb)
{
    const int i = (blockIdx.x * 256 + threadIdx.x) * 8;
    float4 a = *(const float4*)&x[i];
    float4 b = *(const float4*)&x[i + 4];
    ushort4 lo, hi;
    lo.x = f2bf(a.x); lo.y = f2bf(a.y); lo.z = f2bf(a.z); lo.w = f2bf(a.w);
    hi.x = f2bf(b.x); hi.y = f2bf(b.y); hi.z = f2bf(b.z); hi.w = f2bf(b.w);
    *(ushort4*)&xb[i]     = lo;
    *(ushort4*)&xb[i + 4] = hi;
}

// ---------------------------------------------------------------------------
// convert_w: W fp32 [k][n] -> Wt bf16 [mat][n][k] (transposed, n-major)
// ---------------------------------------------------------------------------
__global__ __launch_bounds__(64) void convert_w(
    const float* __restrict__ Wq, const float* __restrict__ Wk,
    const float* __restrict__ Wv, const float* __restrict__ Wo,
    unsigned short* __restrict__ Wt)
{
    const int mat = blockIdx.z;
    const float* W = (mat == 0) ? Wq : (mat == 1) ? Wk : (mat == 2) ? Wv : Wo;
    const int n  = blockIdx.y * 64 + threadIdx.x;
    const int k0 = blockIdx.x * 8;
    ushort4 u0, u1;
    u0.x = f2bf(W[(size_t)(k0 + 0) * D + n]);
    u0.y = f2bf(W[(size_t)(k0 + 1) * D + n]);
    u0.z = f2bf(W[(size_t)(k0 + 2) * D + n]);
    u0.w = f2bf(W[(size_t)(k0 + 3) * D + n]);
    u1.x = f2bf(W[(size_t)(k0 + 4) * D + n]);
    u1.y = f2bf(W[(size_t)(k0 + 5) * D + n]);
    u1.z = f2bf(W[(size_t)(k0 + 6) * D + n]);
    u1.w = f2bf(W[(size_t)(k0 + 7) * D + n]);
    unsigned short* o = Wt + (size_t)mat * D * D + (size_t)n * D + k0;
    *(ushort4*)&o[0] = u0;
    *(ushort4*)&o[4] = u1;
}

// ---------------------------------------------------------------------------
// QKV GEMM, bf16 MFMA 16x16x32. 128x128 tile, BK=32, 4 waves (2x2).
// STATIC dual-buffer (named arrays, unroll-2) — unchanged from round 9.
// ---------------------------------------------------------------------------
__global__ __launch_bounds__(256) void gemm_qkv(
    const unsigned short* __restrict__ xb, const unsigned short* __restrict__ Wt,
    unsigned short* __restrict__ Qb, unsigned short* __restrict__ Kb,
    unsigned short* __restrict__ Vt)
{
    __shared__ unsigned short As0[128 * 32];
    __shared__ unsigned short As1[128 * 32];
    __shared__ unsigned short Bs0[128 * 32];
    __shared__ unsigned short Bs1[128 * 32];

    const int tid = threadIdx.x;
    const int l  = tid & 63;
    const int w  = tid >> 6;
    const int lr = l & 15;
    const int g  = l >> 4;
    const int wr = w >> 1, wc = w & 1;

    const int bm  = blockIdx.y;
    const int bnl = blockIdx.x;          // 0..23
    const int mat = bnl >> 3;            // 0..2
    const int n0  = (bnl & 7) * 128;
    const int m0  = bm * 128;
    const unsigned short* Bp = Wt + (size_t)mat * D * D;

    const int lrow = l >> 2;             // 0..15 row within 16-row chunk
    const int lcol = (l & 3) * 8;        // 0,8,16,24

    f32x4 acc[4][4];
    #pragma unroll
    for (int i = 0; i < 4; ++i)
        #pragma unroll
        for (int j = 0; j < 4; ++j) acc[i][j] = (f32x4){0.f, 0.f, 0.f, 0.f};

#define QKV_STAGE(AD, BD, kk0)                                                    \
    {                                                                             \
        _Pragma("unroll")                                                         \
        for (int p = 0; p < 2; ++p) {                                             \
            const int c = w * 2 + p;                                              \
            gload16(&xb[(size_t)(m0 + c * 16 + lrow) * D + (kk0) + lcol],         \
                    &AD[c * 512]);                                                \
            gload16(&Bp[(size_t)(n0 + c * 16 + lrow) * D + (kk0) + lcol],         \
                    &BD[c * 512]);                                                \
        }                                                                         \
    }

#define QKV_COMP(AS, BS)                                                          \
    {                                                                             \
        bf16x8 af[4], bfr[4];                                                     \
        _Pragma("unroll")                                                         \
        for (int i = 0; i < 4; ++i) {                                             \
            af[i]  = *(const bf16x8*)&AS[(wr * 64 + i * 16 + lr) * 32 + g * 8];   \
            bfr[i] = *(const bf16x8*)&BS[(wc * 64 + i * 16 + lr) * 32 + g * 8];   \
        }                                                                         \
        _Pragma("unroll")                                                         \
        for (int mi = 0; mi < 4; ++mi)                                            \
            _Pragma("unroll")                                                     \
            for (int ni = 0; ni < 4; ++ni)                                        \
                acc[mi][ni] = __builtin_amdgcn_mfma_f32_16x16x32_bf16(            \
                    af[mi], bfr[ni], acc[mi][ni], 0, 0, 0);                       \
    }

    QKV_STAGE(As0, Bs0, 0);
    __syncthreads();
    for (int k0 = 0; k0 < D; k0 += 64) {
        QKV_STAGE(As1, Bs1, k0 + 32);          // k0+32 <= 992 < D always
        QKV_COMP(As0, Bs0);
        __syncthreads();
        if (k0 + 64 < D) QKV_STAGE(As0, Bs0, k0 + 64);
        QKV_COMP(As1, Bs1);
        __syncthreads();
    }
#undef QKV_STAGE
#undef QKV_COMP

    const int b      = m0 >> 11;
    const int s_base = (m0 & (S - 1)) + wr * 64;
    if (mat == 2) {
        #pragma unroll
        for (int ni = 0; ni < 4; ++ni) {
            const int n  = n0 + wc * 64 + ni * 16 + lr;
            const int bh = b * H + (n >> 6);
            unsigned short* vp = Vt + ((size_t)bh * DH + (n & 63)) * S;
            #pragma unroll
            for (int mi = 0; mi < 4; ++mi) {
                const int s0 = s_base + mi * 16 + g * 4;
                ushort4 u;
                u.x = f2bf(acc[mi][ni][0]); u.y = f2bf(acc[mi][ni][1]);
                u.z = f2bf(acc[mi][ni][2]); u.w = f2bf(acc[mi][ni][3]);
                *(ushort4*)&vp[s0] = u;
            }
        }
    } else {
        unsigned short* Op = (mat == 0) ? Qb : Kb;
        #pragma unroll
        for (int mi = 0; mi < 4; ++mi)
            #pragma unroll
            for (int r = 0; r < 4; ++r) {
                const int s = s_base + mi * 16 + g * 4 + r;
                #pragma unroll
                for (int ni = 0; ni < 4; ++ni) {
                    const int n  = n0 + wc * 64 + ni * 16 + lr;
                    const int bh = b * H + (n >> 6);
                    Op[((size_t)bh * S + s) * DH + (n & 63)] = f2bf(acc[mi][ni][r]);
                }
            }
    }
}

// ---------------------------------------------------------------------------
// Output GEMM, bf16 MFMA — now STATIC dual-buffer unroll-2 (proven pattern).
// ---------------------------------------------------------------------------
__global__ __launch_bounds__(256) void gemm_out(
    const unsigned short* __restrict__ ctxb, const unsigned short* __restrict__ Wot,
    const float* __restrict__ bo, float* __restrict__ out)
{
    __shared__ unsigned short As0[64 * 32];
    __shared__ unsigned short As1[64 * 32];
    __shared__ unsigned short Bs0[128 * 32];
    __shared__ unsigned short Bs1[128 * 32];

    const int tid = threadIdx.x;
    const int l  = tid & 63;
    const int w  = tid >> 6;
    const int lr = l & 15;
    const int g  = l >> 4;
    const int wr = w >> 1, wc = w & 1;

    const int m0 = blockIdx.y * 64;
    const int n0 = blockIdx.x * 128;

    const int lrow = l >> 2;
    const int lcol = (l & 3) * 8;

    f32x4 acc[2][4];
    #pragma unroll
    for (int i = 0; i < 2; ++i)
        #pragma unroll
        for (int j = 0; j < 4; ++j) acc[i][j] = (f32x4){0.f, 0.f, 0.f, 0.f};

#define OUT_STAGE(AD, BD, kk0)                                                    \
    {                                                                             \
        gload16(&ctxb[(size_t)(m0 + w * 16 + lrow) * D + (kk0) + lcol],           \
                &AD[w * 512]);                                                    \
        _Pragma("unroll")                                                         \
        for (int p = 0; p < 2; ++p) {                                             \
            const int c = w * 2 + p;                                              \
            gload16(&Wot[(size_t)(n0 + c * 16 + lrow) * D + (kk0) + lcol],        \
                    &BD[c * 512]);                                                \
        }                                                                         \
    }

#define OUT_COMP(AS, BS)                                                          \
    {                                                                             \
        bf16x8 af[2], bfr[4];                                                     \
        _Pragma("unroll")                                                         \
        for (int i = 0; i < 2; ++i)                                               \
            af[i] = *(const bf16x8*)&AS[(wr * 32 + i * 16 + lr) * 32 + g * 8];    \
        _Pragma("unroll")                                                         \
        for (int i = 0; i < 4; ++i)                                               \
            bfr[i] = *(const bf16x8*)&BS[(wc * 64 + i * 16 + lr) * 32 + g * 8];   \
        _Pragma("unroll")                                                         \
        for (int mi = 0; mi < 2; ++mi)                                            \
            _Pragma("unroll")                                                     \
            for (int ni = 0; ni < 4; ++ni)                                        \
                acc[mi][ni] = __builtin_amdgcn_mfma_f32_16x16x32_bf16(            \
                    af[mi], bfr[ni], acc[mi][ni], 0, 0, 0);                       \
    }

    OUT_STAGE(As0, Bs0, 0);
    __syncthreads();
    for (int k0 = 0; k0 < D; k0 += 64) {
        OUT_STAGE(As1, Bs1, k0 + 32);
        OUT_COMP(As0, Bs0);
        __syncthreads();
        if (k0 + 64 < D) OUT_STAGE(As0, Bs0, k0 + 64);
        OUT_COMP(As1, Bs1);
        __syncthreads();
    }
#undef OUT_STAGE
#undef OUT_COMP

    #pragma unroll
    for (int mi = 0; mi < 2; ++mi)
        #pragma unroll
        for (int ni = 0; ni < 4; ++ni) {
            const int n = n0 + wc * 64 + ni * 16 + lr;
            const float bias = bo[n];
            #pragma unroll
            for (int r = 0; r < 4; ++r) {
                const int m = m0 + wr * 32 + mi * 16 + g * 4 + r;
                out[(size_t)m * D + n] = acc[mi][ni][r] + bias;
            }
        }
}

// ---------------------------------------------------------------------------
// Causal flash attention, 32x32x16 bf16 MFMA, swapped operands,
// UNIFORM-WORK blocks: 512 threads = 8 waves. Front team (waves 0-3) does KV
// tiles [0,qt+1), back team (waves 4-7) does [qt+1, 2qt+2) on the SAME
// 32-q-row subtiles; merged via online-softmax combine through an LDS overlay
// (round-5-verified formula). Each block handles the qt pair (15-j, j)
// sequentially -> EVERY wave runs exactly 17 tile-steps (front steps
// (16-j)+(j+1)=17, back the same). Grid 256 = 1 block/CU, XCD-pinned bh.
// Buffers template-selected (attn_side<HALF>) so all LDS addresses are
// compile-time constants (round-9 alias lesson).
// ---------------------------------------------------------------------------
union AttnShared {
    unsigned short stage[8][4096];   // 8 x 8KB: [half*4 + {K0,V0,K1,V1}]
    float mrg[4][64][34];            // merge overlay (valid only between merge barriers)
};

#define ATTN_STAGE(KD, VD, TT)                                                \
    {                                                                         \
        const int kv0s = (TT) * 64;                                           \
        _Pragma("unroll")                                                     \
        for (int p = 0; p < 2; ++p) {                                         \
            const int c   = wq * 2 + p;                                       \
            const int row = c * 8 + srow;                                     \
            gload16(Kp + (size_t)(kv0s + row) * DH + ssw, &KD[c * 512]);      \
            gload16(Vp + (size_t)row * S + kv0s + ssw, &VD[c * 512]);         \
        }                                                                     \
    }

#define ATTN_STEP(KSB, VSB, TT)                                               \
    if ((TT) <= Fw) {                                                         \
        const int kv0  = (TT) * 64;                                           \
        const bool diag = ((TT) == Fw);                                       \
        f32x16 stl = {}, sth = {};                                            \
        _Pragma("unroll")                                                     \
        for (int kk = 0; kk < 4; ++kk) {                                      \
            const int cc = kk * 2 + hi;                                       \
            bf16x8 kl = *(const bf16x8*)&KSB[l31 * 64 + ((cc ^ (l31 & 7)) * 8)]; \
            bf16x8 kh = *(const bf16x8*)&KSB[(32 + l31) * 64 + ((cc ^ (l31 & 7)) * 8)]; \
            stl = __builtin_amdgcn_mfma_f32_32x32x16_bf16(kl, qf[kk], stl, 0, 0, 0); \
            sth = __builtin_amdgcn_mfma_f32_32x32x16_bf16(kh, qf[kk], sth, 0, 0, 0); \
        }                                                                     \
        const int qg = q0w + l31;                                             \
        float sc0[16], sc1[16];                                               \
        float pmax = -3e38f;                                                  \
        _Pragma("unroll")                                                     \
        for (int r = 0; r < 16; ++r) {                                        \
            const int koff = (r & 3) + 8 * (r >> 2) + 4 * hi;                 \
            float a = stl[r] * 0.125f;                                        \
            float b2 = sth[r] * 0.125f;                                       \
            if (diag) {                                                       \
                if (kv0 + koff > qg)      a  = -3e38f;                        \
                if (kv0 + 32 + koff > qg) b2 = -3e38f;                        \
            }                                                                 \
            sc0[r] = a; sc1[r] = b2;                                          \
            pmax = fmaxf(pmax, fmaxf(a, b2));                                 \
        }                                                                     \
        pmax = fmaxf(pmax, __shfl_xor(pmax, 32));                             \
        if (!__all(pmax <= m + 8.f)) {                                        \
            const float newm = fmaxf(m, pmax);                                \
            const float corr = __expf(m - newm);                              \
            ll *= corr;                                                       \
            _Pragma("unroll")                                                 \
            for (int r = 0; r < 16; ++r) { acc0[r] *= corr; acc1[r] *= corr; }\
            m = newm;                                                         \
        }                                                                     \
        float p0[16], p1[16], psum = 0.f;                                     \
        _Pragma("unroll")                                                     \
        for (int r = 0; r < 16; ++r) {                                        \
            p0[r] = __expf(sc0[r] - m); psum += p0[r];                        \
            p1[r] = __expf(sc1[r] - m); psum += p1[r];                        \
        }                                                                     \
        ll += psum + __shfl_xor(psum, 32);                                    \
        unsigned pw[16];                                                      \
        _Pragma("unroll")                                                     \
        for (int tt = 0; tt < 8; ++tt) {                                      \
            pw[tt]     = cvt_pk_bf16(p0[2 * tt], p0[2 * tt + 1]);             \
            pw[8 + tt] = cvt_pk_bf16(p1[2 * tt], p1[2 * tt + 1]);             \
        }                                                                     \
        __builtin_amdgcn_s_setprio(1);                                        \
        _Pragma("unroll")                                                     \
        for (int ck = 0; ck < 4; ++ck) {                                      \
            const int t00 = 2 * ((2 * ck) & 3) + 8 * (ck >> 1);               \
            const int t10 = 2 * ((2 * ck + 1) & 3) + 8 * (ck >> 1);           \
            const unsigned sw0 = hi ? pw[t10]     : pw[t00];                  \
            const unsigned sw1 = hi ? pw[t10 + 1] : pw[t00 + 1];              \
            const unsigned e0i = hi ? pw[t00]     : pw[t10];                  \
            const unsigned e1i = hi ? pw[t00 + 1] : pw[t10 + 1];              \
            const unsigned e0  = __shfl_xor(e0i, 32);                         \
            const unsigned e1  = __shfl_xor(e1i, 32);                         \
            union { unsigned u[4]; bf16x8 v; } pb;                            \
            pb.u[0] = hi ? e0  : sw0;                                         \
            pb.u[1] = hi ? e1  : sw1;                                         \
            pb.u[2] = hi ? sw0 : e0;                                          \
            pb.u[3] = hi ? sw1 : e1;                                          \
            const int cc = ck * 2 + hi;                                       \
            bf16x8 v0 = *(const bf16x8*)&VSB[l31 * 64 + ((cc ^ (l31 & 7)) * 8)]; \
            bf16x8 v1 = *(const bf16x8*)&VSB[(32 + l31) * 64 + ((cc ^ (l31 & 7)) * 8)]; \
            acc0 = __builtin_amdgcn_mfma_f32_32x32x16_bf16(v0, pb.v, acc0, 0, 0, 0); \
            acc1 = __builtin_amdgcn_mfma_f32_32x32x16_bf16(v1, pb.v, acc1, 0, 0, 0); \
        }                                                                     \
        __builtin_amdgcn_s_setprio(0);                                        \
    }

template<int HALF>
__device__ __forceinline__ void attn_side(
    const unsigned short* __restrict__ Qp, const unsigned short* __restrict__ Kp,
    const unsigned short* __restrict__ Vp, unsigned short* __restrict__ opb,
    AttnShared& sh, int jpair, int wq, int l, int l31, int hi, int srow, int ssw)
{
    unsigned short* const K0 = sh.stage[HALF * 4 + 0];
    unsigned short* const V0 = sh.stage[HALF * 4 + 1];
    unsigned short* const K1 = sh.stage[HALF * 4 + 2];
    unsigned short* const V1 = sh.stage[HALF * 4 + 3];

    for (int it = 0; it < 2; ++it) {
        const int qt    = it ? jpair : 15 - jpair;
        const int hB    = qt + 1;            // front: tiles [0,hB)  back: [hB, 2qt+2)
        const int steps = qt + 1;            // identical for both halves
        const int tb0   = HALF ? hB : 0;
        const int q0w   = qt * 128 + wq * 32;
        const int Fw    = q0w >> 6;

        bf16x8 qf[4];
        #pragma unroll
        for (int kk = 0; kk < 4; ++kk)
            qf[kk] = *(const bf16x8*)&Qp[(size_t)(q0w + l31) * DH + kk * 16 + hi * 8];

        f32x16 acc0 = {}, acc1 = {};
        float m = -1e30f, ll = 0.f;

        ATTN_STAGE(K0, V0, tb0);
        __syncthreads();
        int i = 0;
        while (i + 2 <= steps) {
            ATTN_STAGE(K1, V1, tb0 + i + 1);
            ATTN_STEP(K0, V0, tb0 + i);
            __syncthreads();
            if (i + 2 < steps) ATTN_STAGE(K0, V0, tb0 + i + 2);
            ATTN_STEP(K1, V1, tb0 + i + 1);
            __syncthreads();
            i += 2;
        }
        if (i < steps) {                      // odd step count: last tile is in buf0
            ATTN_STEP(K0, V0, tb0 + i);
            __syncthreads();
        }

        // ---- merge (front deposits, back combines + writes ctx) ----
        if (HALF == 0) {
            float* mb = sh.mrg[wq][l];
            #pragma unroll
            for (int r = 0; r < 16; ++r) { mb[r] = acc0[r]; mb[16 + r] = acc1[r]; }
            mb[32] = m; mb[33] = ll;
        }
        __syncthreads();
        if (HALF == 1) {
            const float* mb = sh.mrg[wq][l];
            const float mA = mb[32], lA = mb[33];
            const float ms = fmaxf(m, mA);
            const float cB = __expf(m - ms);
            const float cA = __expf(mA - ms);
            const float inv = 1.f / (ll * cB + lA * cA);
            unsigned short* op = opb + (size_t)(q0w + l31) * D;
            #pragma unroll
            for (int t = 0; t < 8; ++t) {
                const int r0 = 2 * t, r1 = 2 * t + 1;
                const int d  = (r0 & 3) + 8 * (r0 >> 2) + 4 * hi;
                const float a0 = (acc0[r0] * cB + mb[r0]      * cA) * inv;
                const float a1 = (acc0[r1] * cB + mb[r1]      * cA) * inv;
                const float b0 = (acc1[r0] * cB + mb[16 + r0] * cA) * inv;
                const float b1 = (acc1[r1] * cB + mb[16 + r1] * cA) * inv;
                *(unsigned*)&op[d]      = cvt_pk_bf16(a0, a1);
                *(unsigned*)&op[32 + d] = cvt_pk_bf16(b0, b1);
            }
        }
        __syncthreads();                      // protect stage/mrg overlay reuse
    }
}

__global__ __launch_bounds__(512, 2) void attn_mfma32(
    const unsigned short* __restrict__ Qb, const unsigned short* __restrict__ Kb,
    const unsigned short* __restrict__ Vt, unsigned short* __restrict__ ctxb)
{
    __shared__ AttnShared sh;

    const int tid = threadIdx.x;
    const int l   = tid & 63;
    const int w   = tid >> 6;            // 0..7
    const int wq  = w & 3;               // q-subtile within team
    const int l31 = l & 31;
    const int hi  = l >> 5;
    const int srow = l >> 3;             // staging row within chunk (0..7)
    const int ssw  = 8 * ((l & 7) ^ srow);   // pre-swizzled source col (rule 21)

    const int bid = blockIdx.x;          // 0..255, 1 block/CU
    const int xcd = bid & 7;
    const int u   = bid >> 3;            // 0..31
    const int bh  = xcd * 4 + (u >> 3);  // 4 bh per XCD (KV L2-resident)
    const int jpair = u & 7;             // qt pair (15-j, j)

    const unsigned short* Qp = Qb + (size_t)bh * S * DH;
    const unsigned short* Kp = Kb + (size_t)bh * S * DH;
    const unsigned short* Vp = Vt + (size_t)bh * DH * S;
    const int bb = bh >> 4, hh = bh & (H - 1);
    unsigned short* opb = ctxb + (size_t)bb * S * D + hh * DH;

    if (w < 4) attn_side<0>(Qp, Kp, Vp, opb, sh, jpair, wq, l, l31, hi, srow, ssw);
    else       attn_side<1>(Qp, Kp, Vp, opb, sh, jpair, wq, l, l31, hi, srow, ssw);
}

#undef ATTN_STAGE
#undef ATTN_STEP

} // namespace

extern "C" void kernel_launch(void* const* d_in, const int* in_sizes, int n_in,
                              void* d_out, int out_size, void* d_ws, size_t ws_size,
                              hipStream_t stream) {
    const float* x  = (const float*)d_in[0];
    const float* Wq = (const float*)d_in[1];
    const float* Wk = (const float*)d_in[2];
    const float* Wv = (const float*)d_in[3];
    const float* Wo = (const float*)d_in[4];
    const float* bo = (const float*)d_in[5];
    float* out = (float*)d_out;

    // ws (bf16): xb 8MB | Wt 4x2MB | Qb 8MB | Kb 8MB | Vt 8MB | ctxb 8MB = 48MB
    unsigned short* xb   = (unsigned short*)d_ws;
    unsigned short* Wt   = xb + (size_t)M * D;
    unsigned short* Qb   = Wt + (size_t)4 * D * D;
    unsigned short* Kb   = Qb + (size_t)M * D;
    unsigned short* Vtp  = Kb + (size_t)M * D;
    unsigned short* ctxb = Vtp + (size_t)M * D;

    convert_x<<<dim3((M * D) / (256 * 8)), 256, 0, stream>>>(x, xb);
    convert_w<<<dim3(D / 8, D / 64, 4), 64, 0, stream>>>(Wq, Wk, Wv, Wo, Wt);
    gemm_qkv<<<dim3(24, M / 128), 256, 0, stream>>>(xb, Wt, Qb, Kb, Vtp);
    attn_mfma32<<<dim3(256), 512, 0, stream>>>(Qb, Kb, Vtp, ctxb);
    gemm_out<<<dim3(D / 128, M / 64), 256, 0, stream>>>(
        ctxb, Wt + (size_t)3 * D * D, bo, out);
}